// Round 14
// baseline (327.594 us; speedup 1.0000x reference)
//
#include <hip/hip_runtime.h>

#define CH 128
#define SCAN_B 256
#define SPAD 136     // LDS row stride in ushorts (+16B pad -> 2-way bank alias = free)
#define NPASS 4      // gather src-window passes (window ~3.2MB bf16 fits 4MB XCD L2)

typedef short bf16x8 __attribute__((ext_vector_type(8)));
typedef float f32x4 __attribute__((ext_vector_type(4)));
typedef unsigned short u16x8 __attribute__((ext_vector_type(8)));

static __device__ __forceinline__ unsigned short f2bf(float f) {
    unsigned int u = __float_as_uint(f);
    u = (u + 0x7fff + ((u >> 16) & 1)) >> 16;   // RNE
    return (unsigned short)u;
}
static __device__ __forceinline__ float bf2f(unsigned short s) {
    return __uint_as_float(((unsigned int)s) << 16);
}

// ---------------------------------------------------------------------------
// Fused prep: [0, xBlocks)        : fp32->bf16 feature conversion
//             [xBlocks, +wBlocks) : 5 weight matrices -> bf16 transposed
//             [.., +edgeBlocks)   : dst-degree histogram
__global__ __launch_bounds__(256) void prep_kernel(
    const float* __restrict__ x, unsigned short* __restrict__ xb, int total4,
    const float* __restrict__ w0, const float* __restrict__ w1,
    const float* __restrict__ w2, const float* __restrict__ w3,
    const float* __restrict__ w4,
    unsigned short* __restrict__ t0, unsigned short* __restrict__ t1,
    unsigned short* __restrict__ t2, unsigned short* __restrict__ t3,
    unsigned short* __restrict__ t4,
    const int* __restrict__ dst, int* __restrict__ cnt, int E,
    int xBlocks, int wBlocks) {
    int b = blockIdx.x;
    if (b < xBlocks) {
        int idx = b * 256 + threadIdx.x;
        if (idx < total4) {
            float4 v = ((const float4*)x)[idx];
            ushort4 o;
            o.x = f2bf(v.x); o.y = f2bf(v.y); o.z = f2bf(v.z); o.w = f2bf(v.w);
            ((ushort4*)xb)[idx] = o;
        }
    } else if (b < xBlocks + wBlocks) {
        int idx = (b - xBlocks) * 256 + threadIdx.x;   // 0..81919
        int wsel = idx >> 14;                          // 16384 elems per matrix
        int r = idx & 16383;
        const float* W; unsigned short* T;
        switch (wsel) {
            case 0: W = w0; T = t0; break;
            case 1: W = w1; T = t1; break;
            case 2: W = w2; T = t2; break;
            case 3: W = w3; T = t3; break;
            default: W = w4; T = t4; break;
        }
        T[(r & 127) * CH + (r >> 7)] = f2bf(W[r]);
    } else {
        int e = (b - xBlocks - wBlocks) * 256 + threadIdx.x;
        if (e < E) atomicAdd(&cnt[dst[e]], 1);
    }
}

// ---------------------------------------------------------------------------
__global__ __launch_bounds__(256) void scan_partial_kernel(const int* __restrict__ cnt,
                                                           int* __restrict__ blockSums,
                                                           int n) {
    __shared__ int red[256];
    const int tid = threadIdx.x;
    const int i = blockIdx.x * SCAN_B + tid;
    red[tid] = (i < n) ? cnt[i] : 0;
    __syncthreads();
#pragma unroll
    for (int off = 128; off > 0; off >>= 1) {
        if (tid < off) red[tid] += red[tid + off];
        __syncthreads();
    }
    if (tid == 0) blockSums[blockIdx.x] = red[0];
}

// Fused phase-2 scan: block b reduces predecessors' partials in LDS, then
// local 256-chunk exclusive scan. Requires scanBlocks <= 256.
__global__ __launch_bounds__(256) void scan_final_kernel(const int* __restrict__ cnt,
                                                         const int* __restrict__ blockSums,
                                                         int* __restrict__ rowptr,
                                                         int* __restrict__ cursor,
                                                         int n, int E) {
    __shared__ int s[256];
    __shared__ int blkoff;
    const int tid = threadIdx.x;

    s[tid] = (tid < (int)blockIdx.x) ? blockSums[tid] : 0;
    __syncthreads();
#pragma unroll
    for (int off = 128; off > 0; off >>= 1) {
        if (tid < off) s[tid] += s[tid + off];
        __syncthreads();
    }
    if (tid == 0) blkoff = s[0];
    __syncthreads();

    const int i = blockIdx.x * SCAN_B + tid;
    int v = (i < n) ? cnt[i] : 0;
    s[tid] = v;
    __syncthreads();
    for (int off = 1; off < 256; off <<= 1) {
        int t = (tid >= off) ? s[tid - off] : 0;
        __syncthreads();
        s[tid] += t;
        __syncthreads();
    }
    if (i < n) {
        int ex = blkoff + s[tid] - v;
        rowptr[i] = ex;
        cursor[i] = ex;
    }
    if (blockIdx.x == 0 && tid == 0) rowptr[n] = E;
}

__global__ __launch_bounds__(256) void fill_kernel(const int* __restrict__ src,
                                                   const int* __restrict__ dst,
                                                   int* __restrict__ cursor,
                                                   int* __restrict__ col, int E) {
    int e = blockIdx.x * 256 + threadIdx.x;
    if (e < E) {
        int pos = atomicAdd(&cursor[dst[e]], 1);
        col[pos] = src[e];
    }
}

// ---------------------------------------------------------------------------
// Gather v5: windowed multi-pass (cache-blocked random reads).
// 32 lanes/node in 2 x 16-lane parity half-groups; lane owns 8 channels.
// NPASS passes over the neighbor list, loading only rows in the pass's
// src-window (~3.2MB bf16 -> every XCD's L2 caches the same window).
// Accumulators persist in registers across passes; combine via shfl_xor(16).
__global__ __launch_bounds__(256) void gather_kernel(const unsigned short* __restrict__ feat,
                                                     const int* __restrict__ rowptr,
                                                     const int* __restrict__ col,
                                                     unsigned short* __restrict__ agg,
                                                     int n, int winsz) {
    const int node = blockIdx.x * 8 + (threadIdx.x >> 5);
    if (node >= n) return;
    const int lane5 = threadIdx.x & 31;
    const int g = lane5 >> 4;               // half-group: even/odd edges
    const int c8 = (lane5 & 15) << 3;
    const int beg = rowptr[node];
    const int end = rowptr[node + 1];

    float acc[8];
#pragma unroll
    for (int j = 0; j < 8; ++j) acc[j] = 0.f;

    for (int pass = 0; pass < NPASS; ++pass) {
        const int lo = pass * winsz;
        const int hi = lo + winsz;
        int i = beg + g;
        for (; i + 6 < end; i += 8) {       // 4 neighbors/lane/iter (stride 2)
            int s0 = col[i], s1 = col[i + 2], s2 = col[i + 4], s3 = col[i + 6];
            if (s0 >= lo && s0 < hi) {
                u16x8 v = *(const u16x8*)&feat[(size_t)s0 * CH + c8];
#pragma unroll
                for (int j = 0; j < 8; ++j) acc[j] += bf2f(v[j]);
            }
            if (s1 >= lo && s1 < hi) {
                u16x8 v = *(const u16x8*)&feat[(size_t)s1 * CH + c8];
#pragma unroll
                for (int j = 0; j < 8; ++j) acc[j] += bf2f(v[j]);
            }
            if (s2 >= lo && s2 < hi) {
                u16x8 v = *(const u16x8*)&feat[(size_t)s2 * CH + c8];
#pragma unroll
                for (int j = 0; j < 8; ++j) acc[j] += bf2f(v[j]);
            }
            if (s3 >= lo && s3 < hi) {
                u16x8 v = *(const u16x8*)&feat[(size_t)s3 * CH + c8];
#pragma unroll
                for (int j = 0; j < 8; ++j) acc[j] += bf2f(v[j]);
            }
        }
        for (; i < end; i += 2) {
            int s0 = col[i];
            if (s0 >= lo && s0 < hi) {
                u16x8 v = *(const u16x8*)&feat[(size_t)s0 * CH + c8];
#pragma unroll
                for (int j = 0; j < 8; ++j) acc[j] += bf2f(v[j]);
            }
        }
    }

    // combine the two parity half-groups (lane ^ 16 stays within the node)
#pragma unroll
    for (int j = 0; j < 8; ++j) acc[j] += __shfl_xor(acc[j], 16, 64);

    if (g == 0) {
        float inv = 1.0f / (float)max(end - beg, 1);
        u16x8 o;
#pragma unroll
        for (int j = 0; j < 8; ++j) o[j] = f2bf(acc[j] * inv);
        *(u16x8*)&agg[(size_t)node * CH + c8] = o;
    }
}

// ---------------------------------------------------------------------------
// SAGE layer GEMM (layer 1): Cb = bf16( relu(A1@Wl + A2@Wr + bias) ).
// Block = 256 thr = 4 waves; wave = 32 rows x 128 cols. No LDS.
__global__ __launch_bounds__(256) void sage_gemm_kernel(
    const unsigned short* __restrict__ A1, const unsigned short* __restrict__ A2,
    const unsigned short* __restrict__ Wt1, const unsigned short* __restrict__ Wt2,
    const float* __restrict__ bias,
    unsigned short* __restrict__ Cb, int n) {
    const int tid = threadIdx.x;
    const int wave = tid >> 6;
    const int lane = tid & 63;
    const int quad = lane >> 4;
    const int l15 = lane & 15;
    const int m0 = blockIdx.x * 128 + wave * 32;

    f32x4 acc[2][8];
#pragma unroll
    for (int t = 0; t < 2; ++t)
#pragma unroll
        for (int u = 0; u < 8; ++u) acc[t][u] = (f32x4){0.f, 0.f, 0.f, 0.f};

    const unsigned short* As[2] = {A1, A2};
    const unsigned short* Ws[2] = {Wt1, Wt2};

    for (int ph = 0; ph < 2; ++ph) {
        const unsigned short* A = As[ph];
        const unsigned short* Wt = Ws[ph];
#pragma unroll
        for (int kb = 0; kb < CH; kb += 32) {
            bf16x8 a[2], b[8];
#pragma unroll
            for (int t = 0; t < 2; ++t) {
                int row = min(m0 + t * 16 + l15, n - 1);     // clamp; store guarded
                a[t] = *(const bf16x8*)&A[(size_t)row * CH + kb + quad * 8];
            }
#pragma unroll
            for (int u = 0; u < 8; ++u)
                b[u] = *(const bf16x8*)&Wt[(size_t)(u * 16 + l15) * CH + kb + quad * 8];
#pragma unroll
            for (int t = 0; t < 2; ++t)
#pragma unroll
                for (int u = 0; u < 8; ++u)
                    acc[t][u] = __builtin_amdgcn_mfma_f32_16x16x32_bf16(
                        a[t], b[u], acc[t][u], 0, 0, 0);
        }
    }

    float bv[8];
#pragma unroll
    for (int u = 0; u < 8; ++u) bv[u] = bias[u * 16 + l15];

#pragma unroll
    for (int t = 0; t < 2; ++t) {
#pragma unroll
        for (int r = 0; r < 4; ++r) {
            int row = m0 + t * 16 + quad * 4 + r;
            if (row >= n) continue;
            size_t base = (size_t)row * CH;
#pragma unroll
            for (int u = 0; u < 8; ++u)
                Cb[base + u * 16 + l15] = f2bf(fmaxf(acc[t][u][r] + bv[u], 0.f));
        }
    }
}

// ---------------------------------------------------------------------------
// Fused layer-2 + decoder. Block = 256 thr = 4 waves, 128 rows.
// Phase 1: ob_tile = relu(A1@W2l + A2@W2r + b2) -> LDS (bf16, padded rows).
// Phase 2: out = alpha*(ob_tile@Wd + bd) + (1-alpha)*bf2f(xb).
// Each wave reads only LDS rows it wrote -> no __syncthreads needed.
__global__ __launch_bounds__(256) void sage_dec_kernel(
    const unsigned short* __restrict__ A1, const unsigned short* __restrict__ A2,
    const unsigned short* __restrict__ Wt1, const unsigned short* __restrict__ Wt2,
    const float* __restrict__ bias2,
    const unsigned short* __restrict__ Wdt, const float* __restrict__ biasd,
    const float* __restrict__ alpha_p, const unsigned short* __restrict__ residb,
    float* __restrict__ Cf, int n) {
    __shared__ unsigned short sOb[128 * SPAD];   // 34.8 KB

    const int tid = threadIdx.x;
    const int wave = tid >> 6;
    const int lane = tid & 63;
    const int quad = lane >> 4;
    const int l15 = lane & 15;
    const int m0 = blockIdx.x * 128 + wave * 32;
    const int lrow0 = wave * 32;                 // this wave's local row base

    // ---- Phase 1: layer-2 SAGE GEMM -> LDS ----
    {
        f32x4 acc[2][8];
#pragma unroll
        for (int t = 0; t < 2; ++t)
#pragma unroll
            for (int u = 0; u < 8; ++u) acc[t][u] = (f32x4){0.f, 0.f, 0.f, 0.f};

        const unsigned short* As[2] = {A1, A2};
        const unsigned short* Ws[2] = {Wt1, Wt2};
        for (int ph = 0; ph < 2; ++ph) {
            const unsigned short* A = As[ph];
            const unsigned short* Wt = Ws[ph];
#pragma unroll
            for (int kb = 0; kb < CH; kb += 32) {
                bf16x8 a[2], b[8];
#pragma unroll
                for (int t = 0; t < 2; ++t) {
                    int row = min(m0 + t * 16 + l15, n - 1);
                    a[t] = *(const bf16x8*)&A[(size_t)row * CH + kb + quad * 8];
                }
#pragma unroll
                for (int u = 0; u < 8; ++u)
                    b[u] = *(const bf16x8*)&Wt[(size_t)(u * 16 + l15) * CH + kb + quad * 8];
#pragma unroll
                for (int t = 0; t < 2; ++t)
#pragma unroll
                    for (int u = 0; u < 8; ++u)
                        acc[t][u] = __builtin_amdgcn_mfma_f32_16x16x32_bf16(
                            a[t], b[u], acc[t][u], 0, 0, 0);
            }
        }

        float bv[8];
#pragma unroll
        for (int u = 0; u < 8; ++u) bv[u] = bias2[u * 16 + l15];

#pragma unroll
        for (int t = 0; t < 2; ++t)
#pragma unroll
            for (int r = 0; r < 4; ++r) {
                int lr = lrow0 + t * 16 + quad * 4 + r;      // local row < 128
#pragma unroll
                for (int u = 0; u < 8; ++u)
                    sOb[lr * SPAD + u * 16 + l15] =
                        f2bf(fmaxf(acc[t][u][r] + bv[u], 0.f));
            }
    }
    // No barrier: each wave reads back only its own 32 LDS rows below.

    // ---- Phase 2: decoder GEMM, A from LDS ----
    {
        f32x4 acc[2][8];
#pragma unroll
        for (int t = 0; t < 2; ++t)
#pragma unroll
            for (int u = 0; u < 8; ++u) acc[t][u] = (f32x4){0.f, 0.f, 0.f, 0.f};

#pragma unroll
        for (int kb = 0; kb < CH; kb += 32) {
            bf16x8 a[2], b[8];
#pragma unroll
            for (int t = 0; t < 2; ++t)
                a[t] = *(const bf16x8*)&sOb[(lrow0 + t * 16 + l15) * SPAD + kb + quad * 8];
#pragma unroll
            for (int u = 0; u < 8; ++u)
                b[u] = *(const bf16x8*)&Wdt[(size_t)(u * 16 + l15) * CH + kb + quad * 8];
#pragma unroll
            for (int t = 0; t < 2; ++t)
#pragma unroll
                for (int u = 0; u < 8; ++u)
                    acc[t][u] = __builtin_amdgcn_mfma_f32_16x16x32_bf16(
                        a[t], b[u], acc[t][u], 0, 0, 0);
        }

        float bv[8];
#pragma unroll
        for (int u = 0; u < 8; ++u) bv[u] = biasd[u * 16 + l15];
        const float al = alpha_p[0], be = 1.0f - al;

#pragma unroll
        for (int t = 0; t < 2; ++t)
#pragma unroll
            for (int r = 0; r < 4; ++r) {
                int row = m0 + t * 16 + quad * 4 + r;
                if (row >= n) continue;
                size_t base = (size_t)row * CH;
#pragma unroll
                for (int u = 0; u < 8; ++u) {
                    int colj = u * 16 + l15;
                    Cf[base + colj] = al * (acc[t][u][r] + bv[u]) +
                                      be * bf2f(residb[base + colj]);
                }
            }
    }
}

// ---------------------------------------------------------------------------
extern "C" void kernel_launch(void* const* d_in, const int* in_sizes, int n_in,
                              void* d_out, int out_size, void* d_ws, size_t ws_size,
                              hipStream_t stream) {
    const float* x    = (const float*)d_in[0];
    const int*   ei   = (const int*)d_in[1];
    const float* W1_l = (const float*)d_in[2];
    const float* b1   = (const float*)d_in[3];
    const float* W1_r = (const float*)d_in[4];
    const float* W2_l = (const float*)d_in[5];
    const float* b2   = (const float*)d_in[6];
    const float* W2_r = (const float*)d_in[7];
    const float* Wd   = (const float*)d_in[8];
    const float* bd   = (const float*)d_in[9];
    const float* alpha = (const float*)d_in[10];
    float* out = (float*)d_out;

    const int n = in_sizes[0] / CH;
    const int E = in_sizes[1] / 2;
    const int* src = ei;
    const int* dst = ei + E;

    const size_t nCH = (size_t)n * CH;
    const int scanBlocks = (n + SCAN_B - 1) / SCAN_B;    // 196 (must be <= 256)
    const int winsz = (n + NPASS - 1) / NPASS;           // 12500

    unsigned short* xb   = (unsigned short*)d_ws;        // [n,CH] bf16 (kept pristine)
    unsigned short* hb   = xb + nCH;                     // [n,CH] bf16
    unsigned short* aggb = hb + nCH;                     // [n,CH] bf16
    unsigned short* w1lt = aggb + nCH;                   // 5 x [CH,CH] bf16 transposed
    unsigned short* w1rt = w1lt + CH * CH;
    unsigned short* w2lt = w1rt + CH * CH;
    unsigned short* w2rt = w2lt + CH * CH;
    unsigned short* wdt  = w2rt + CH * CH;
    int* cnt    = (int*)(wdt + CH * CH);                 // [n]
    int* rowptr = cnt + n;                               // [n+1]
    int* cursor = rowptr + n + 1;                        // [n]
    int* col    = cursor + n;                            // [E]
    int* bsums  = col + E;                               // [scanBlocks]

    const int edgeBlocks = (E + 255) / 256;              // 2500
    const int xBlocks = (int)((nCH / 4 + 255) / 256);    // 6250
    const int wBlocks = 5 * CH * CH / 256;               // 320
    const int gatherBlocks = (n + 7) / 8;                // 6250
    const int gemmBlocks = (n + 127) / 128;              // 391

    // ---- CSR build + conversions ----
    hipMemsetAsync(cnt, 0, (size_t)n * sizeof(int), stream);
    prep_kernel<<<xBlocks + wBlocks + edgeBlocks, 256, 0, stream>>>(
        x, xb, (int)(nCH / 4),
        W1_l, W1_r, W2_l, W2_r, Wd, w1lt, w1rt, w2lt, w2rt, wdt,
        dst, cnt, E, xBlocks, wBlocks);
    scan_partial_kernel<<<scanBlocks, 256, 0, stream>>>(cnt, bsums, n);
    scan_final_kernel<<<scanBlocks, 256, 0, stream>>>(cnt, bsums, rowptr, cursor, n, E);
    fill_kernel<<<edgeBlocks, 256, 0, stream>>>(src, dst, cursor, col, E);

    // ---- layer 1: hb = relu(agg(xb)@W1_l + xb@W1_r + b1) ----
    gather_kernel<<<gatherBlocks, 256, 0, stream>>>(xb, rowptr, col, aggb, n, winsz);
    sage_gemm_kernel<<<gemmBlocks, 256, 0, stream>>>(
        aggb, xb, w1lt, w1rt, b1, hb, n);
    // ---- layer 2 + decoder (fused; ob never hits global):
    //      out = alpha*(relu(agg(hb)@W2_l + hb@W2_r + b2)@Wd + bd) + (1-alpha)*xb
    gather_kernel<<<gatherBlocks, 256, 0, stream>>>(hb, rowptr, col, aggb, n, winsz);
    sage_dec_kernel<<<gemmBlocks, 256, 0, stream>>>(
        aggb, hb, w2lt, w2rt, b2, wdt, bd, alpha, xb, out, n);
}

// Round 15
// 269.353 us; speedup vs baseline: 1.2162x; 1.2162x over previous
//
#include <hip/hip_runtime.h>

#define CH 128
#define SCAN_B 256
#define SPAD 136   // LDS row stride in ushorts (+16B pad -> 2-way bank alias = free)

typedef short bf16x8 __attribute__((ext_vector_type(8)));
typedef float f32x4 __attribute__((ext_vector_type(4)));
typedef unsigned short u16x8 __attribute__((ext_vector_type(8)));

static __device__ __forceinline__ unsigned short f2bf(float f) {
    unsigned int u = __float_as_uint(f);
    u = (u + 0x7fff + ((u >> 16) & 1)) >> 16;   // RNE
    return (unsigned short)u;
}
static __device__ __forceinline__ float bf2f(unsigned short s) {
    return __uint_as_float(((unsigned int)s) << 16);
}

// ---------------------------------------------------------------------------
// Fused prep: [0, xBlocks)        : fp32->bf16 feature conversion
//             [xBlocks, +wBlocks) : 5 weight matrices -> bf16 transposed
//             [.., +edgeBlocks)   : dst-degree histogram
__global__ __launch_bounds__(256) void prep_kernel(
    const float* __restrict__ x, unsigned short* __restrict__ xb, int total4,
    const float* __restrict__ w0, const float* __restrict__ w1,
    const float* __restrict__ w2, const float* __restrict__ w3,
    const float* __restrict__ w4,
    unsigned short* __restrict__ t0, unsigned short* __restrict__ t1,
    unsigned short* __restrict__ t2, unsigned short* __restrict__ t3,
    unsigned short* __restrict__ t4,
    const int* __restrict__ dst, int* __restrict__ cnt, int E,
    int xBlocks, int wBlocks) {
    int b = blockIdx.x;
    if (b < xBlocks) {
        int idx = b * 256 + threadIdx.x;
        if (idx < total4) {
            float4 v = ((const float4*)x)[idx];
            ushort4 o;
            o.x = f2bf(v.x); o.y = f2bf(v.y); o.z = f2bf(v.z); o.w = f2bf(v.w);
            ((ushort4*)xb)[idx] = o;
        }
    } else if (b < xBlocks + wBlocks) {
        int idx = (b - xBlocks) * 256 + threadIdx.x;   // 0..81919
        int wsel = idx >> 14;                          // 16384 elems per matrix
        int r = idx & 16383;
        const float* W; unsigned short* T;
        switch (wsel) {
            case 0: W = w0; T = t0; break;
            case 1: W = w1; T = t1; break;
            case 2: W = w2; T = t2; break;
            case 3: W = w3; T = t3; break;
            default: W = w4; T = t4; break;
        }
        T[(r & 127) * CH + (r >> 7)] = f2bf(W[r]);
    } else {
        int e = (b - xBlocks - wBlocks) * 256 + threadIdx.x;
        if (e < E) atomicAdd(&cnt[dst[e]], 1);
    }
}

// ---------------------------------------------------------------------------
__global__ __launch_bounds__(256) void scan_partial_kernel(const int* __restrict__ cnt,
                                                           int* __restrict__ blockSums,
                                                           int n) {
    __shared__ int red[256];
    const int tid = threadIdx.x;
    const int i = blockIdx.x * SCAN_B + tid;
    red[tid] = (i < n) ? cnt[i] : 0;
    __syncthreads();
#pragma unroll
    for (int off = 128; off > 0; off >>= 1) {
        if (tid < off) red[tid] += red[tid + off];
        __syncthreads();
    }
    if (tid == 0) blockSums[blockIdx.x] = red[0];
}

// Fused phase-2 scan: block b reduces predecessors' partials in LDS, then
// local 256-chunk exclusive scan. Requires scanBlocks <= 256.
__global__ __launch_bounds__(256) void scan_final_kernel(const int* __restrict__ cnt,
                                                         const int* __restrict__ blockSums,
                                                         int* __restrict__ rowptr,
                                                         int* __restrict__ cursor,
                                                         int n, int E) {
    __shared__ int s[256];
    __shared__ int blkoff;
    const int tid = threadIdx.x;

    s[tid] = (tid < (int)blockIdx.x) ? blockSums[tid] : 0;
    __syncthreads();
#pragma unroll
    for (int off = 128; off > 0; off >>= 1) {
        if (tid < off) s[tid] += s[tid + off];
        __syncthreads();
    }
    if (tid == 0) blkoff = s[0];
    __syncthreads();

    const int i = blockIdx.x * SCAN_B + tid;
    int v = (i < n) ? cnt[i] : 0;
    s[tid] = v;
    __syncthreads();
    for (int off = 1; off < 256; off <<= 1) {
        int t = (tid >= off) ? s[tid - off] : 0;
        __syncthreads();
        s[tid] += t;
        __syncthreads();
    }
    if (i < n) {
        int ex = blkoff + s[tid] - v;
        rowptr[i] = ex;
        cursor[i] = ex;
    }
    if (blockIdx.x == 0 && tid == 0) rowptr[n] = E;
}

__global__ __launch_bounds__(256) void fill_kernel(const int* __restrict__ src,
                                                   const int* __restrict__ dst,
                                                   int* __restrict__ cursor,
                                                   int* __restrict__ col, int E) {
    int e = blockIdx.x * 256 + threadIdx.x;
    if (e < E) {
        int pos = atomicAdd(&cursor[dst[e]], 1);
        col[pos] = src[e];
    }
}

// ---------------------------------------------------------------------------
// Gather (R13 best): 32 lanes/node, split into 2 x 16-lane half-groups taking
// even/odd neighbors (halves serial depth + straggler tail), lane owns
// 8 channels (16B loads). Cross-half combine via shfl_xor(16). 8 nodes/block.
__global__ __launch_bounds__(256) void gather_kernel(const unsigned short* __restrict__ feat,
                                                     const int* __restrict__ rowptr,
                                                     const int* __restrict__ col,
                                                     unsigned short* __restrict__ agg, int n) {
    const int node = blockIdx.x * 8 + (threadIdx.x >> 5);
    if (node >= n) return;
    const int lane5 = threadIdx.x & 31;     // position within the node's 32 lanes
    const int g = lane5 >> 4;               // half-group: 0 = even edges, 1 = odd
    const int c8 = (lane5 & 15) << 3;
    const int beg = rowptr[node];
    const int end = rowptr[node + 1];

    float acc[8];
#pragma unroll
    for (int j = 0; j < 8; ++j) acc[j] = 0.f;

    int i = beg + g;
    for (; i + 6 < end; i += 8) {           // 4 neighbors/lane/iter (stride 2)
        int s0 = col[i], s1 = col[i + 2], s2 = col[i + 4], s3 = col[i + 6];
        u16x8 v0 = *(const u16x8*)&feat[(size_t)s0 * CH + c8];
        u16x8 v1 = *(const u16x8*)&feat[(size_t)s1 * CH + c8];
        u16x8 v2 = *(const u16x8*)&feat[(size_t)s2 * CH + c8];
        u16x8 v3 = *(const u16x8*)&feat[(size_t)s3 * CH + c8];
#pragma unroll
        for (int j = 0; j < 8; ++j)
            acc[j] += (bf2f(v0[j]) + bf2f(v1[j])) + (bf2f(v2[j]) + bf2f(v3[j]));
    }
    for (; i < end; i += 2) {
        u16x8 v0 = *(const u16x8*)&feat[(size_t)col[i] * CH + c8];
#pragma unroll
        for (int j = 0; j < 8; ++j) acc[j] += bf2f(v0[j]);
    }

    // combine the two half-group partials (lane ^ 16 stays within the node)
#pragma unroll
    for (int j = 0; j < 8; ++j) acc[j] += __shfl_xor(acc[j], 16, 64);

    if (g == 0) {
        float inv = 1.0f / (float)max(end - beg, 1);
        u16x8 o;
#pragma unroll
        for (int j = 0; j < 8; ++j) o[j] = f2bf(acc[j] * inv);
        *(u16x8*)&agg[(size_t)node * CH + c8] = o;
    }
}

// ---------------------------------------------------------------------------
// SAGE layer GEMM (layer 1): Cb = bf16( relu(A1@Wl + A2@Wr + bias) ).
// Block = 256 thr = 4 waves; wave = 32 rows x 128 cols. No LDS.
__global__ __launch_bounds__(256) void sage_gemm_kernel(
    const unsigned short* __restrict__ A1, const unsigned short* __restrict__ A2,
    const unsigned short* __restrict__ Wt1, const unsigned short* __restrict__ Wt2,
    const float* __restrict__ bias,
    unsigned short* __restrict__ Cb, int n) {
    const int tid = threadIdx.x;
    const int wave = tid >> 6;
    const int lane = tid & 63;
    const int quad = lane >> 4;
    const int l15 = lane & 15;
    const int m0 = blockIdx.x * 128 + wave * 32;

    f32x4 acc[2][8];
#pragma unroll
    for (int t = 0; t < 2; ++t)
#pragma unroll
        for (int u = 0; u < 8; ++u) acc[t][u] = (f32x4){0.f, 0.f, 0.f, 0.f};

    const unsigned short* As[2] = {A1, A2};
    const unsigned short* Ws[2] = {Wt1, Wt2};

    for (int ph = 0; ph < 2; ++ph) {
        const unsigned short* A = As[ph];
        const unsigned short* Wt = Ws[ph];
#pragma unroll
        for (int kb = 0; kb < CH; kb += 32) {
            bf16x8 a[2], b[8];
#pragma unroll
            for (int t = 0; t < 2; ++t) {
                int row = min(m0 + t * 16 + l15, n - 1);     // clamp; store guarded
                a[t] = *(const bf16x8*)&A[(size_t)row * CH + kb + quad * 8];
            }
#pragma unroll
            for (int u = 0; u < 8; ++u)
                b[u] = *(const bf16x8*)&Wt[(size_t)(u * 16 + l15) * CH + kb + quad * 8];
#pragma unroll
            for (int t = 0; t < 2; ++t)
#pragma unroll
                for (int u = 0; u < 8; ++u)
                    acc[t][u] = __builtin_amdgcn_mfma_f32_16x16x32_bf16(
                        a[t], b[u], acc[t][u], 0, 0, 0);
        }
    }

    float bv[8];
#pragma unroll
    for (int u = 0; u < 8; ++u) bv[u] = bias[u * 16 + l15];

#pragma unroll
    for (int t = 0; t < 2; ++t) {
#pragma unroll
        for (int r = 0; r < 4; ++r) {
            int row = m0 + t * 16 + quad * 4 + r;
            if (row >= n) continue;
            size_t base = (size_t)row * CH;
#pragma unroll
            for (int u = 0; u < 8; ++u)
                Cb[base + u * 16 + l15] = f2bf(fmaxf(acc[t][u][r] + bv[u], 0.f));
        }
    }
}

// ---------------------------------------------------------------------------
// Fused layer-2 + decoder. Block = 256 thr = 4 waves, 128 rows.
// Phase 1: ob_tile = relu(A1@W2l + A2@W2r + b2) -> LDS (bf16, padded rows).
// Phase 2: out = alpha*(ob_tile@Wd + bd) + (1-alpha)*bf2f(xb).
// Each wave reads only LDS rows it wrote -> no __syncthreads needed.
__global__ __launch_bounds__(256) void sage_dec_kernel(
    const unsigned short* __restrict__ A1, const unsigned short* __restrict__ A2,
    const unsigned short* __restrict__ Wt1, const unsigned short* __restrict__ Wt2,
    const float* __restrict__ bias2,
    const unsigned short* __restrict__ Wdt, const float* __restrict__ biasd,
    const float* __restrict__ alpha_p, const unsigned short* __restrict__ residb,
    float* __restrict__ Cf, int n) {
    __shared__ unsigned short sOb[128 * SPAD];   // 34.8 KB

    const int tid = threadIdx.x;
    const int wave = tid >> 6;
    const int lane = tid & 63;
    const int quad = lane >> 4;
    const int l15 = lane & 15;
    const int m0 = blockIdx.x * 128 + wave * 32;
    const int lrow0 = wave * 32;                 // this wave's local row base

    // ---- Phase 1: layer-2 SAGE GEMM -> LDS ----
    {
        f32x4 acc[2][8];
#pragma unroll
        for (int t = 0; t < 2; ++t)
#pragma unroll
            for (int u = 0; u < 8; ++u) acc[t][u] = (f32x4){0.f, 0.f, 0.f, 0.f};

        const unsigned short* As[2] = {A1, A2};
        const unsigned short* Ws[2] = {Wt1, Wt2};
        for (int ph = 0; ph < 2; ++ph) {
            const unsigned short* A = As[ph];
            const unsigned short* Wt = Ws[ph];
#pragma unroll
            for (int kb = 0; kb < CH; kb += 32) {
                bf16x8 a[2], b[8];
#pragma unroll
                for (int t = 0; t < 2; ++t) {
                    int row = min(m0 + t * 16 + l15, n - 1);
                    a[t] = *(const bf16x8*)&A[(size_t)row * CH + kb + quad * 8];
                }
#pragma unroll
                for (int u = 0; u < 8; ++u)
                    b[u] = *(const bf16x8*)&Wt[(size_t)(u * 16 + l15) * CH + kb + quad * 8];
#pragma unroll
                for (int t = 0; t < 2; ++t)
#pragma unroll
                    for (int u = 0; u < 8; ++u)
                        acc[t][u] = __builtin_amdgcn_mfma_f32_16x16x32_bf16(
                            a[t], b[u], acc[t][u], 0, 0, 0);
            }
        }

        float bv[8];
#pragma unroll
        for (int u = 0; u < 8; ++u) bv[u] = bias2[u * 16 + l15];

#pragma unroll
        for (int t = 0; t < 2; ++t)
#pragma unroll
            for (int r = 0; r < 4; ++r) {
                int lr = lrow0 + t * 16 + quad * 4 + r;      // local row < 128
#pragma unroll
                for (int u = 0; u < 8; ++u)
                    sOb[lr * SPAD + u * 16 + l15] =
                        f2bf(fmaxf(acc[t][u][r] + bv[u], 0.f));
            }
    }
    // No barrier: each wave reads back only its own 32 LDS rows below.

    // ---- Phase 2: decoder GEMM, A from LDS ----
    {
        f32x4 acc[2][8];
#pragma unroll
        for (int t = 0; t < 2; ++t)
#pragma unroll
            for (int u = 0; u < 8; ++u) acc[t][u] = (f32x4){0.f, 0.f, 0.f, 0.f};

#pragma unroll
        for (int kb = 0; kb < CH; kb += 32) {
            bf16x8 a[2], b[8];
#pragma unroll
            for (int t = 0; t < 2; ++t)
                a[t] = *(const bf16x8*)&sOb[(lrow0 + t * 16 + l15) * SPAD + kb + quad * 8];
#pragma unroll
            for (int u = 0; u < 8; ++u)
                b[u] = *(const bf16x8*)&Wdt[(size_t)(u * 16 + l15) * CH + kb + quad * 8];
#pragma unroll
            for (int t = 0; t < 2; ++t)
#pragma unroll
                for (int u = 0; u < 8; ++u)
                    acc[t][u] = __builtin_amdgcn_mfma_f32_16x16x32_bf16(
                        a[t], b[u], acc[t][u], 0, 0, 0);
        }

        float bv[8];
#pragma unroll
        for (int u = 0; u < 8; ++u) bv[u] = biasd[u * 16 + l15];
        const float al = alpha_p[0], be = 1.0f - al;

#pragma unroll
        for (int t = 0; t < 2; ++t)
#pragma unroll
            for (int r = 0; r < 4; ++r) {
                int row = m0 + t * 16 + quad * 4 + r;
                if (row >= n) continue;
                size_t base = (size_t)row * CH;
#pragma unroll
                for (int u = 0; u < 8; ++u) {
                    int colj = u * 16 + l15;
                    Cf[base + colj] = al * (acc[t][u][r] + bv[u]) +
                                      be * bf2f(residb[base + colj]);
                }
            }
    }
}

// ---------------------------------------------------------------------------
extern "C" void kernel_launch(void* const* d_in, const int* in_sizes, int n_in,
                              void* d_out, int out_size, void* d_ws, size_t ws_size,
                              hipStream_t stream) {
    const float* x    = (const float*)d_in[0];
    const int*   ei   = (const int*)d_in[1];
    const float* W1_l = (const float*)d_in[2];
    const float* b1   = (const float*)d_in[3];
    const float* W1_r = (const float*)d_in[4];
    const float* W2_l = (const float*)d_in[5];
    const float* b2   = (const float*)d_in[6];
    const float* W2_r = (const float*)d_in[7];
    const float* Wd   = (const float*)d_in[8];
    const float* bd   = (const float*)d_in[9];
    const float* alpha = (const float*)d_in[10];
    float* out = (float*)d_out;

    const int n = in_sizes[0] / CH;
    const int E = in_sizes[1] / 2;
    const int* src = ei;
    const int* dst = ei + E;

    const size_t nCH = (size_t)n * CH;
    const int scanBlocks = (n + SCAN_B - 1) / SCAN_B;    // 196 (must be <= 256)

    unsigned short* xb   = (unsigned short*)d_ws;        // [n,CH] bf16 (kept pristine)
    unsigned short* hb   = xb + nCH;                     // [n,CH] bf16
    unsigned short* aggb = hb + nCH;                     // [n,CH] bf16
    unsigned short* w1lt = aggb + nCH;                   // 5 x [CH,CH] bf16 transposed
    unsigned short* w1rt = w1lt + CH * CH;
    unsigned short* w2lt = w1rt + CH * CH;
    unsigned short* w2rt = w2lt + CH * CH;
    unsigned short* wdt  = w2rt + CH * CH;
    int* cnt    = (int*)(wdt + CH * CH);                 // [n]
    int* rowptr = cnt + n;                               // [n+1]
    int* cursor = rowptr + n + 1;                        // [n]
    int* col    = cursor + n;                            // [E]
    int* bsums  = col + E;                               // [scanBlocks]

    const int edgeBlocks = (E + 255) / 256;              // 2500
    const int xBlocks = (int)((nCH / 4 + 255) / 256);    // 6250
    const int wBlocks = 5 * CH * CH / 256;               // 320
    const int gatherBlocks = (n + 7) / 8;                // 6250
    const int gemmBlocks = (n + 127) / 128;              // 391

    // ---- CSR build + conversions ----
    hipMemsetAsync(cnt, 0, (size_t)n * sizeof(int), stream);
    prep_kernel<<<xBlocks + wBlocks + edgeBlocks, 256, 0, stream>>>(
        x, xb, (int)(nCH / 4),
        W1_l, W1_r, W2_l, W2_r, Wd, w1lt, w1rt, w2lt, w2rt, wdt,
        dst, cnt, E, xBlocks, wBlocks);
    scan_partial_kernel<<<scanBlocks, 256, 0, stream>>>(cnt, bsums, n);
    scan_final_kernel<<<scanBlocks, 256, 0, stream>>>(cnt, bsums, rowptr, cursor, n, E);
    fill_kernel<<<edgeBlocks, 256, 0, stream>>>(src, dst, cursor, col, E);

    // ---- layer 1: hb = relu(agg(xb)@W1_l + xb@W1_r + b1) ----
    gather_kernel<<<gatherBlocks, 256, 0, stream>>>(xb, rowptr, col, aggb, n);
    sage_gemm_kernel<<<gemmBlocks, 256, 0, stream>>>(
        aggb, xb, w1lt, w1rt, b1, hb, n);
    // ---- layer 2 + decoder (fused; ob never hits global):
    //      out = alpha*(relu(agg(hb)@W2_l + hb@W2_r + b2)@Wd + bd) + (1-alpha)*xb
    gather_kernel<<<gatherBlocks, 256, 0, stream>>>(hb, rowptr, col, aggb, n);
    sage_dec_kernel<<<gemmBlocks, 256, 0, stream>>>(
        aggb, hb, w2lt, w2rt, b2, wdt, bd, alpha, xb, out, n);
}